// Round 1
// baseline (1018.066 us; speedup 1.0000x reference)
//
#include <hip/hip_runtime.h>
#include <math.h>

// Problem constants (N,C,H,W) = (8,64,256,256); blocks 16x16 -> k in [0,256), j in [0,256)
#define HH 256
#define WW 256
#define HW (HH*WW)            // 65536
#define NEG_BIG -1e30f
#define NORM_EPS 5e-5f

// ws float-element offsets (total 42,483,712 floats = ~162 MB required in d_ws)
#define OFF_WASMT   0            // 4096   : w_asm transposed  [ci][c]
#define OFF_WMATT   4096         // 9216   : w_match transposed [ci][dy][dx][e]
#define OFF_RNORM   16384        // 524288 : 1/max(||q||,eps)  [n][k][j]
#define OFF_QBLK    540672       // 8388608: Q blockified      [n][k][j][16]
#define OFF_VBLK    8929280      // 33554432: V blockified     [n][k][j][64]  (reused as O output)

// ---------------------------------------------------------------- weights transpose
__global__ void k_transpose_w(const float* __restrict__ w_asm,
                              const float* __restrict__ w_match,
                              float* __restrict__ ws) {
    int t = threadIdx.x;
    float* wasmT = ws + OFF_WASMT;
    float* wmatT = ws + OFF_WMATT;
    for (int idx = t; idx < 64 * 64; idx += 256) {
        int ci = idx >> 6, c = idx & 63;
        wasmT[ci * 64 + c] = w_asm[c * 64 + ci];
    }
    for (int idx = t; idx < 576 * 16; idx += 256) {
        int e = idx & 15, r = idx >> 4;            // r = ci*9 + dy*3 + dx
        wmatT[idx] = w_match[e * 576 + r];
    }
}

// ---------------------------------------------------------------- conv1x1 -> Vblk
__global__ __launch_bounds__(256) void k_conv1x1(const float* __restrict__ x,
                                                 const float* __restrict__ b_asm,
                                                 const float* __restrict__ ws_r,
                                                 float* __restrict__ vblk) {
    int p = blockIdx.x * 256 + threadIdx.x;       // pixel id over N*H*W
    int n = p >> 16;
    int h = (p >> 8) & 255;
    int w = p & 255;
    const float* wasmT = ws_r + OFF_WASMT;

    float acc[64];
#pragma unroll
    for (int c = 0; c < 64; ++c) acc[c] = b_asm[c];

    const float* xp = x + n * (64 * HW) + h * WW + w;
#pragma unroll 4
    for (int ci = 0; ci < 64; ++ci) {
        float xv = xp[ci * HW];                    // coalesced across lanes (w consecutive)
        const float* wr = wasmT + ci * 64;         // uniform address -> scalar loads
#pragma unroll
        for (int c = 0; c < 64; ++c) acc[c] = fmaf(xv, wr[c], acc[c]);
    }

    int k = ((h & 15) << 4) | (w & 15);
    int j = ((h >> 4) << 4) | (w >> 4);
    float* out = vblk + (size_t)(((n << 8) | k) * 256 + j) * 64;
#pragma unroll
    for (int c4 = 0; c4 < 16; ++c4) {
        reinterpret_cast<float4*>(out)[c4] =
            make_float4(acc[c4 * 4], acc[c4 * 4 + 1], acc[c4 * 4 + 2], acc[c4 * 4 + 3]);
    }
}

// ---------------------------------------------------------------- conv3x3 -> Qblk + rnorm
__global__ __launch_bounds__(256) void k_conv3x3(const float* __restrict__ x,
                                                 const float* __restrict__ b_match,
                                                 const float* __restrict__ ws_r,
                                                 float* __restrict__ qblk,
                                                 float* __restrict__ rnorm) {
    int p = blockIdx.x * 256 + threadIdx.x;
    int n = p >> 16;
    int h = (p >> 8) & 255;
    int w = p & 255;
    const float* wmatT = ws_r + OFF_WMATT;

    float acc[16];
#pragma unroll
    for (int e = 0; e < 16; ++e) acc[e] = b_match[e];

    const float* xb = x + n * (64 * HW) + h * WW + w;
    bool hm = h > 0, hp = h < 255, wmk = w > 0, wpk = w < 255;

    for (int ci = 0; ci < 64; ++ci) {
        const float* xc = xb + ci * HW;
        float xv[9];
        xv[0] = (hm && wmk) ? xc[-WW - 1] : 0.f;
        xv[1] = hm          ? xc[-WW]     : 0.f;
        xv[2] = (hm && wpk) ? xc[-WW + 1] : 0.f;
        xv[3] = wmk         ? xc[-1]      : 0.f;
        xv[4] =               xc[0];
        xv[5] = wpk         ? xc[1]       : 0.f;
        xv[6] = (hp && wmk) ? xc[WW - 1]  : 0.f;
        xv[7] = hp          ? xc[WW]      : 0.f;
        xv[8] = (hp && wpk) ? xc[WW + 1]  : 0.f;
        const float* wr = wmatT + ci * 144;        // uniform address -> scalar loads
#pragma unroll
        for (int t9 = 0; t9 < 9; ++t9) {
            float v = xv[t9];
#pragma unroll
            for (int e = 0; e < 16; ++e) acc[e] = fmaf(v, wr[t9 * 16 + e], acc[e]);
        }
    }

    float ss = 0.f;
#pragma unroll
    for (int e = 0; e < 16; ++e) ss = fmaf(acc[e], acc[e], ss);
    float rn = 1.0f / fmaxf(sqrtf(ss), NORM_EPS);

    int k = ((h & 15) << 4) | (w & 15);
    int j = ((h >> 4) << 4) | (w >> 4);
    size_t base = (size_t)(((n << 8) | k) * 256 + j);
    rnorm[base] = rn;
    float* out = qblk + base * 16;
#pragma unroll
    for (int e4 = 0; e4 < 4; ++e4) {
        reinterpret_cast<float4*>(out)[e4] =
            make_float4(acc[e4 * 4], acc[e4 * 4 + 1], acc[e4 * 4 + 2], acc[e4 * 4 + 3]);
    }
}

// ---------------------------------------------------------------- attention per (n,k)
// score[i][j] = softmax_j( (q_i . q_j) * rn[j] , diag=-inf );  O[i][c] = sum_j score * V[j][c]
// Writes O over the block's own V slab (all V reads complete before the epilogue).
__global__ __launch_bounds__(256) void k_attn(const float* __restrict__ ws_r,
                                              float* __restrict__ vblk) {
    __shared__ float Qs[256 * 16];     // 16 KB
    __shared__ float RNs[256];
    __shared__ float Vt[64 * 64];      // 16 KB

    int b = blockIdx.x;                // n*256 + k
    int i = threadIdx.x;               // row (output block index)
    const float* qbase  = ws_r + OFF_QBLK  + (size_t)b * (256 * 16);
    const float* rnbase = ws_r + OFF_RNORM + (size_t)b * 256;
    float* vbase = vblk + (size_t)b * (256 * 64);

    // stage Q + rn into LDS (coalesced)
    const float4* q4  = reinterpret_cast<const float4*>(qbase);
    float4*       qs4 = reinterpret_cast<float4*>(Qs);
#pragma unroll
    for (int r = 0; r < 4; ++r) qs4[i + 256 * r] = q4[i + 256 * r];
    RNs[i] = rnbase[i];

    // own row from global (contiguous 64B per lane)
    float q[16];
#pragma unroll
    for (int r = 0; r < 4; ++r) {
        float4 t4 = q4[i * 4 + r];
        q[r * 4 + 0] = t4.x; q[r * 4 + 1] = t4.y; q[r * 4 + 2] = t4.z; q[r * 4 + 3] = t4.w;
    }
    __syncthreads();

    const float4* qsc = reinterpret_cast<const float4*>(Qs);

    // pass 1: row max (diag excluded)
    float m = NEG_BIG;
#pragma unroll 2
    for (int j = 0; j < 256; ++j) {
        float s = 0.f;
#pragma unroll
        for (int r = 0; r < 4; ++r) {
            float4 qq = qsc[j * 4 + r];            // broadcast LDS read
            s = fmaf(q[r * 4 + 0], qq.x, s); s = fmaf(q[r * 4 + 1], qq.y, s);
            s = fmaf(q[r * 4 + 2], qq.z, s); s = fmaf(q[r * 4 + 3], qq.w, s);
        }
        s *= RNs[j];
        m = (j == i) ? m : fmaxf(m, s);
    }

    // pass 2: accumulate unnormalized O and the denominator l
    float o[64];
#pragma unroll
    for (int c = 0; c < 64; ++c) o[c] = 0.f;
    float l = 0.f;

    for (int jt = 0; jt < 4; ++jt) {
        __syncthreads();                           // previous Vt fully consumed
        const float4* v4  = reinterpret_cast<const float4*>(vbase + jt * (64 * 64));
        float4*       vt4 = reinterpret_cast<float4*>(Vt);
#pragma unroll
        for (int r = 0; r < 4; ++r) vt4[i + 256 * r] = v4[i + 256 * r];
        __syncthreads();

        const float4* vtc = reinterpret_cast<const float4*>(Vt);
        for (int jj = 0; jj < 64; ++jj) {
            int j = jt * 64 + jj;
            float s = 0.f;
#pragma unroll
            for (int r = 0; r < 4; ++r) {
                float4 qq = qsc[j * 4 + r];
                s = fmaf(q[r * 4 + 0], qq.x, s); s = fmaf(q[r * 4 + 1], qq.y, s);
                s = fmaf(q[r * 4 + 2], qq.z, s); s = fmaf(q[r * 4 + 3], qq.w, s);
            }
            s *= RNs[j];
            float pe = __expf(s - m);
            float pv = (j == i) ? 0.f : pe;
            l += pv;
#pragma unroll
            for (int c4 = 0; c4 < 16; ++c4) {
                float4 vv = vtc[jj * 16 + c4];     // broadcast LDS read
                o[c4 * 4 + 0] = fmaf(pv, vv.x, o[c4 * 4 + 0]);
                o[c4 * 4 + 1] = fmaf(pv, vv.y, o[c4 * 4 + 1]);
                o[c4 * 4 + 2] = fmaf(pv, vv.z, o[c4 * 4 + 2]);
                o[c4 * 4 + 3] = fmaf(pv, vv.w, o[c4 * 4 + 3]);
            }
        }
    }

    float linv = 1.0f / l;
#pragma unroll
    for (int c = 0; c < 64; ++c) o[c] *= linv;

    __syncthreads();                               // everyone done reading V globally/LDS
    float* ob = vbase + (size_t)i * 64;            // overwrite V slab with O
#pragma unroll
    for (int c4 = 0; c4 < 16; ++c4) {
        reinterpret_cast<float4*>(ob)[c4] =
            make_float4(o[c4 * 4], o[c4 * 4 + 1], o[c4 * 4 + 2], o[c4 * 4 + 3]);
    }
}

// ---------------------------------------------------------------- unblockify + residual
// block = (n,h); lanes carry c (coalesced Oblk gather), per-lane contiguous x/out rows.
__global__ __launch_bounds__(256) void k_unblock(const float* __restrict__ oblk,
                                                 const float* __restrict__ x,
                                                 float* __restrict__ out) {
    int b = blockIdx.x;                 // n*256 + h
    int n = b >> 8, h = b & 255;
    int t = threadIdx.x;
    int c = t & 63, wq = t >> 6;        // lane=c, 4 w-quarters across waves
    int kh = h & 15, jh = h >> 4;

    const float* ob = oblk + ((size_t)n << 22);           // n * 256*256*64
    size_t xoff = (((size_t)(n * 64 + c)) << 16) + ((size_t)h << 8);
    const float4* xr   = reinterpret_cast<const float4*>(x + xoff);
    float4*       outr = reinterpret_cast<float4*>(out + xoff);

    for (int it = 0; it < 16; ++it) {
        int w4 = wq * 16 + it;          // float4 index within the row
        int w0 = w4 * 4;
        float vals[4];
#pragma unroll
        for (int r = 0; r < 4; ++r) {
            int w = w0 + r;
            int wm = w & 15, wd = w >> 4;
            vals[r] = ob[(((size_t)(kh * 16 + wm)) << 14) + ((jh * 16 + wd) << 6) + c];
        }
        float4 xv = xr[w4];
        outr[w4] = make_float4(vals[0] + xv.x, vals[1] + xv.y, vals[2] + xv.z, vals[3] + xv.w);
    }
}

// ---------------------------------------------------------------- launch
extern "C" void kernel_launch(void* const* d_in, const int* in_sizes, int n_in,
                              void* d_out, int out_size, void* d_ws, size_t ws_size,
                              hipStream_t stream) {
    const float* x       = (const float*)d_in[0];
    const float* w_match = (const float*)d_in[1];
    const float* b_match = (const float*)d_in[2];
    const float* w_asm   = (const float*)d_in[3];
    const float* b_asm   = (const float*)d_in[4];
    float* out = (float*)d_out;
    float* ws  = (float*)d_ws;
    // requires ws_size >= ~162 MB (42,483,712 floats)

    k_transpose_w<<<1, 256, 0, stream>>>(w_asm, w_match, ws);
    k_conv1x1<<<2048, 256, 0, stream>>>(x, b_asm, ws, ws + OFF_VBLK);
    k_conv3x3<<<2048, 256, 0, stream>>>(x, b_match, ws, ws + OFF_QBLK, ws + OFF_RNORM);
    k_attn<<<2048, 256, 0, stream>>>(ws, ws + OFF_VBLK);
    k_unblock<<<2048, 256, 0, stream>>>(ws + OFF_VBLK, x, out);
}

// Round 3
// 704.122 us; speedup vs baseline: 1.4459x; 1.4459x over previous
//
#include <hip/hip_runtime.h>
#include <math.h>

typedef __attribute__((ext_vector_type(8))) short bf16x8;   // 8 bf16 (4 VGPR) MFMA A/B frag
typedef __attribute__((ext_vector_type(4))) float f32x4;    // MFMA C/D frag

#define HH 256
#define WW 256
#define HW (HH*WW)
#define NORM_EPS 5e-5f

// ws float-element offsets (~162 MB)
#define OFF_WASMT   0
#define OFF_WMATT   4096
#define OFF_RNORM   16384
#define OFF_QBLK    540672
#define OFF_VBLK    8929280

// ---------------------------------------------------------------- weights transpose
__global__ void k_transpose_w(const float* __restrict__ w_asm,
                              const float* __restrict__ w_match,
                              float* __restrict__ ws) {
    int t = threadIdx.x;
    float* wasmT = ws + OFF_WASMT;
    float* wmatT = ws + OFF_WMATT;
    for (int idx = t; idx < 64 * 64; idx += 256) {
        int ci = idx >> 6, c = idx & 63;
        wasmT[ci * 64 + c] = w_asm[c * 64 + ci];
    }
    for (int idx = t; idx < 576 * 16; idx += 256) {
        int e = idx & 15, r = idx >> 4;
        wmatT[idx] = w_match[e * 576 + r];
    }
}

// ---------------------------------------------------------------- conv1x1 -> Vblk
__global__ __launch_bounds__(256) void k_conv1x1(const float* __restrict__ x,
                                                 const float* __restrict__ b_asm,
                                                 const float* __restrict__ ws_r,
                                                 float* __restrict__ vblk) {
    int p = blockIdx.x * 256 + threadIdx.x;
    int n = p >> 16;
    int h = (p >> 8) & 255;
    int w = p & 255;
    const float* wasmT = ws_r + OFF_WASMT;

    float acc[64];
#pragma unroll
    for (int c = 0; c < 64; ++c) acc[c] = b_asm[c];

    const float* xp = x + n * (64 * HW) + h * WW + w;
#pragma unroll 4
    for (int ci = 0; ci < 64; ++ci) {
        float xv = xp[ci * HW];
        const float* wr = wasmT + ci * 64;
#pragma unroll
        for (int c = 0; c < 64; ++c) acc[c] = fmaf(xv, wr[c], acc[c]);
    }

    int k = ((h & 15) << 4) | (w & 15);
    int j = ((h >> 4) << 4) | (w >> 4);
    float* out = vblk + (size_t)(((n << 8) | k) * 256 + j) * 64;
#pragma unroll
    for (int c4 = 0; c4 < 16; ++c4) {
        reinterpret_cast<float4*>(out)[c4] =
            make_float4(acc[c4 * 4], acc[c4 * 4 + 1], acc[c4 * 4 + 2], acc[c4 * 4 + 3]);
    }
}

// ---------------------------------------------------------------- conv3x3 -> Qblk + rnorm
__global__ __launch_bounds__(256) void k_conv3x3(const float* __restrict__ x,
                                                 const float* __restrict__ b_match,
                                                 const float* __restrict__ ws_r,
                                                 float* __restrict__ qblk,
                                                 float* __restrict__ rnorm) {
    int p = blockIdx.x * 256 + threadIdx.x;
    int n = p >> 16;
    int h = (p >> 8) & 255;
    int w = p & 255;
    const float* wmatT = ws_r + OFF_WMATT;

    float acc[16];
#pragma unroll
    for (int e = 0; e < 16; ++e) acc[e] = b_match[e];

    const float* xb = x + n * (64 * HW) + h * WW + w;
    bool hm = h > 0, hp = h < 255, wmk = w > 0, wpk = w < 255;

    for (int ci = 0; ci < 64; ++ci) {
        const float* xc = xb + ci * HW;
        float xv[9];
        xv[0] = (hm && wmk) ? xc[-WW - 1] : 0.f;
        xv[1] = hm          ? xc[-WW]     : 0.f;
        xv[2] = (hm && wpk) ? xc[-WW + 1] : 0.f;
        xv[3] = wmk         ? xc[-1]      : 0.f;
        xv[4] =               xc[0];
        xv[5] = wpk         ? xc[1]       : 0.f;
        xv[6] = (hp && wmk) ? xc[WW - 1]  : 0.f;
        xv[7] = hp          ? xc[WW]      : 0.f;
        xv[8] = (hp && wpk) ? xc[WW + 1]  : 0.f;
        const float* wr = wmatT + ci * 144;
#pragma unroll
        for (int t9 = 0; t9 < 9; ++t9) {
            float v = xv[t9];
#pragma unroll
            for (int e = 0; e < 16; ++e) acc[e] = fmaf(v, wr[t9 * 16 + e], acc[e]);
        }
    }

    float ss = 0.f;
#pragma unroll
    for (int e = 0; e < 16; ++e) ss = fmaf(acc[e], acc[e], ss);
    float rn = 1.0f / fmaxf(sqrtf(ss), NORM_EPS);

    int k = ((h & 15) << 4) | (w & 15);
    int j = ((h >> 4) << 4) | (w >> 4);
    size_t base = (size_t)(((n << 8) | k) * 256 + j);
    rnorm[base] = rn;
    float* out = qblk + base * 16;
#pragma unroll
    for (int e4 = 0; e4 < 4; ++e4) {
        reinterpret_cast<float4*>(out)[e4] =
            make_float4(acc[e4 * 4], acc[e4 * 4 + 1], acc[e4 * 4 + 2], acc[e4 * 4 + 3]);
    }
}

// ---------------------------------------------------------------- MFMA attention per (n,k)
// S^T = K.Q^T with split-bf16 (hi/lo); two-pass softmax; O^T = V^T.P^T with split V/P.
// LDS layout (bytes):
//   QP  = 0     : Q_pair [256 rows][40 bf16] (80 B rows): slots 0-15 qh, 16-31 ql
//   KP  = 20480 : K_pair same layout, K = Q*rn folded
//   VTH = 40960 : Vt hi  [64 c][72 bf16] (144 B rows)   -- chunk of 64 j
//   VTL = 50176 : Vt lo  same
//   PB  = 59392 : per-wave P staging [16 i][20 dwords] (80 B rows), 1280 B/wave
//   O-transpose reuses VTH region: per-wave [16 i][68 f32] (272 B rows), 4352 B/wave
#define QP  0
#define KP  20480
#define VTH 40960
#define VTL 50176
#define PB  59392

#define MFMA16(A,B,C) __builtin_amdgcn_mfma_f32_16x16x32_bf16((A),(B),(C),0,0,0)

__global__ __launch_bounds__(256, 2) void k_attn(const float* __restrict__ ws_r,
                                                 float* __restrict__ vblk) {
    __shared__ __align__(16) unsigned char sm[64512];
    const int tid  = threadIdx.x;
    const int lane = tid & 63;
    const int wv   = tid >> 6;
    const int g    = lane >> 4;
    const int l15  = lane & 15;
    const bool hi32 = lane >= 32;
    const int b = blockIdx.x;

    const bf16x8 zfrag = {0,0,0,0,0,0,0,0};

    const float* qbase  = ws_r + OFF_QBLK  + (size_t)b * (256 * 16);
    const float* rnbase = ws_r + OFF_RNORM + (size_t)b * 256;
    float* vbase = vblk + (size_t)b * (256 * 64);

    // ---- stage Q/K into LDS as split bf16 (rn folded into K)
    {
        const int t = tid;                     // row j
        float rn = rnbase[t];
        const float4* q4 = reinterpret_cast<const float4*>(qbase + t * 16);
        float q[16];
#pragma unroll
        for (int r = 0; r < 4; ++r) {
            float4 v = q4[r];
            q[4*r+0] = v.x; q[4*r+1] = v.y; q[4*r+2] = v.z; q[4*r+3] = v.w;
        }
        unsigned qh[8], ql[8], kh[8], kl[8];
#pragma unroll
        for (int e = 0; e < 8; ++e) {
            float a0 = q[2*e], a1 = q[2*e+1];
            unsigned u0 = __float_as_uint(a0) & 0xFFFF0000u;
            unsigned u1 = __float_as_uint(a1) & 0xFFFF0000u;
            float r0 = a0 - __uint_as_float(u0);
            float r1 = a1 - __uint_as_float(u1);
            qh[e] = (u0 >> 16) | u1;
            ql[e] = ((__float_as_uint(r0) & 0xFFFF0000u) >> 16) | (__float_as_uint(r1) & 0xFFFF0000u);
            float k0 = a0 * rn, k1 = a1 * rn;
            unsigned v0 = __float_as_uint(k0) & 0xFFFF0000u;
            unsigned v1 = __float_as_uint(k1) & 0xFFFF0000u;
            float s0 = k0 - __uint_as_float(v0);
            float s1 = k1 - __uint_as_float(v1);
            kh[e] = (v0 >> 16) | v1;
            kl[e] = ((__float_as_uint(s0) & 0xFFFF0000u) >> 16) | (__float_as_uint(s1) & 0xFFFF0000u);
        }
        uint4* qrow = reinterpret_cast<uint4*>(sm + QP + t * 80);
        qrow[0] = make_uint4(qh[0], qh[1], qh[2], qh[3]);
        qrow[1] = make_uint4(qh[4], qh[5], qh[6], qh[7]);
        qrow[2] = make_uint4(ql[0], ql[1], ql[2], ql[3]);
        qrow[3] = make_uint4(ql[4], ql[5], ql[6], ql[7]);
        uint4* krow = reinterpret_cast<uint4*>(sm + KP + t * 80);
        krow[0] = make_uint4(kh[0], kh[1], kh[2], kh[3]);
        krow[1] = make_uint4(kh[4], kh[5], kh[6], kh[7]);
        krow[2] = make_uint4(kl[0], kl[1], kl[2], kl[3]);
        krow[3] = make_uint4(kl[4], kl[5], kl[6], kl[7]);
    }
    __syncthreads();

    // ---- hold Q B-operand frags in registers for the whole kernel
    bf16x8 qb1[4], qb2[4];
#pragma unroll
    for (int it = 0; it < 4; ++it) {
        int i0 = wv * 64 + it * 16;
        qb1[it] = *reinterpret_cast<const bf16x8*>(sm + QP + (i0 + l15) * 80 + (g & 1) * 16);
        bf16x8 t2 = *reinterpret_cast<const bf16x8*>(sm + QP + (i0 + l15) * 80 + 32 + (g & 1) * 16);
        qb2[it] = hi32 ? zfrag : t2;           // [ql | 0]
    }

    // ---- pass 1: row max (over j) per output row i  (lane's col = l15)
    float mrow[4] = {-1e30f, -1e30f, -1e30f, -1e30f};
    for (int jt = 0; jt < 16; ++jt) {
        bf16x8 kf = *reinterpret_cast<const bf16x8*>(sm + KP + (jt * 16 + l15) * 80 + g * 16);
#pragma unroll
        for (int it = 0; it < 4; ++it) {
            f32x4 s = {0.f, 0.f, 0.f, 0.f};
            s = MFMA16(kf, qb1[it], s);
            s = MFMA16(kf, qb2[it], s);
            bool dtile = (jt * 16 == wv * 64 + it * 16);
#pragma unroll
            for (int r = 0; r < 4; ++r) {
                float v = s[r];
                if (dtile && (4 * g + r == l15)) v = -1e30f;
                mrow[it] = fmaxf(mrow[it], v);
            }
        }
    }
#pragma unroll
    for (int it = 0; it < 4; ++it) {
        float m = mrow[it];
        m = fmaxf(m, __shfl_xor(m, 16, 64));
        m = fmaxf(m, __shfl_xor(m, 32, 64));
        mrow[it] = m;
    }

    // ---- pass 2: P = exp(S-m) split bf16 -> O^T accum
    float lsum[4] = {0.f, 0.f, 0.f, 0.f};
    f32x4 acc[4][4];
#pragma unroll
    for (int it = 0; it < 4; ++it)
#pragma unroll
        for (int ct = 0; ct < 4; ++ct) acc[it][ct] = (f32x4){0.f, 0.f, 0.f, 0.f};

    for (int ch = 0; ch < 4; ++ch) {
        __syncthreads();                       // previous chunk's Vt fully consumed
        {   // stage V chunk: 64 j x 64 c, split hi/lo, transposed [c][j]
            int c = tid >> 2, jq = tid & 3;
            const float* vg = vbase + (size_t)(ch * 64) * 64 + c;
#pragma unroll
            for (int s2 = 0; s2 < 8; ++s2) {
                int jl = jq * 16 + s2 * 2;
                float v0 = vg[(size_t)jl * 64];
                float v1 = vg[(size_t)(jl + 1) * 64];
                unsigned u0 = __float_as_uint(v0) & 0xFFFF0000u;
                unsigned u1 = __float_as_uint(v1) & 0xFFFF0000u;
                float r0 = v0 - __uint_as_float(u0);
                float r1 = v1 - __uint_as_float(u1);
                *reinterpret_cast<unsigned*>(sm + VTH + c * 144 + jl * 2) = (u0 >> 16) | u1;
                *reinterpret_cast<unsigned*>(sm + VTL + c * 144 + jl * 2) =
                    ((__float_as_uint(r0) & 0xFFFF0000u) >> 16) | (__float_as_uint(r1) & 0xFFFF0000u);
            }
        }
        __syncthreads();

#pragma unroll
        for (int jt = 0; jt < 4; ++jt) {
            int jg0 = ch * 64 + jt * 16;
            int jl0 = jt * 16;
            bf16x8 kf = *reinterpret_cast<const bf16x8*>(sm + KP + (jg0 + l15) * 80 + g * 16);
            bf16x8 vh[4], vl[4];
#pragma unroll
            for (int ct = 0; ct < 4; ++ct) {
                vh[ct] = *reinterpret_cast<const bf16x8*>(
                    sm + VTH + (ct * 16 + l15) * 144 + (jl0 + 8 * (g & 1)) * 2);
                bf16x8 t2 = *reinterpret_cast<const bf16x8*>(
                    sm + VTL + (ct * 16 + l15) * 144 + (jl0 + 8 * (g & 1)) * 2);
                vl[ct] = hi32 ? zfrag : t2;    // [Vl | 0]
            }
#pragma unroll
            for (int it = 0; it < 4; ++it) {
                f32x4 s = {0.f, 0.f, 0.f, 0.f};
                s = MFMA16(kf, qb1[it], s);
                s = MFMA16(kf, qb2[it], s);
                bool dtile = (jg0 == wv * 64 + it * 16);
                unsigned pd[4];
#pragma unroll
                for (int r = 0; r < 4; ++r) {
                    float p = __expf(s[r] - mrow[it]);
                    if (dtile && (4 * g + r == l15)) p = 0.f;
                    lsum[it] += p;
                    unsigned uh = __float_as_uint(p) & 0xFFFF0000u;
                    float lo = p - __uint_as_float(uh);
                    unsigned ul = __float_as_uint(lo) & 0xFFFF0000u;
                    pd[r] = (uh >> 16) | ul;   // lo16 = Ph, hi16 = Pl
                }
                // stage P tile (wave-private, no barrier)
                *reinterpret_cast<uint4*>(sm + PB + wv * 1280 + l15 * 80 + g * 16) =
                    make_uint4(pd[0], pd[1], pd[2], pd[3]);
                const uint4 d0 = *reinterpret_cast<const uint4*>(sm + PB + wv * 1280 + l15 * 80 + (g & 1) * 32);
                const uint4 d1 = *reinterpret_cast<const uint4*>(sm + PB + wv * 1280 + l15 * 80 + (g & 1) * 32 + 16);
                unsigned bw0, bw1, bw2, bw3;
                if (!hi32) {                   // Ph halves
                    bw0 = (d0.x & 0xFFFFu) | (d0.y << 16);
                    bw1 = (d0.z & 0xFFFFu) | (d0.w << 16);
                    bw2 = (d1.x & 0xFFFFu) | (d1.y << 16);
                    bw3 = (d1.z & 0xFFFFu) | (d1.w << 16);
                } else {                       // Pl halves
                    bw0 = (d0.x >> 16) | (d0.y & 0xFFFF0000u);
                    bw1 = (d0.z >> 16) | (d0.w & 0xFFFF0000u);
                    bw2 = (d1.x >> 16) | (d1.y & 0xFFFF0000u);
                    bw3 = (d1.z >> 16) | (d1.w & 0xFFFF0000u);
                }
                union { uint4 u; bf16x8 s8; } pb_u;
                pb_u.u = make_uint4(bw0, bw1, bw2, bw3);
                bf16x8 pb = pb_u.s8;
#pragma unroll
                for (int ct = 0; ct < 4; ++ct) {
                    acc[it][ct] = MFMA16(vh[ct], pb, acc[it][ct]);
                    acc[it][ct] = MFMA16(vl[ct], pb, acc[it][ct]);
                }
            }
        }
    }

    // ---- finalize: l reduce, transpose O^T -> O rows via LDS, coalesced store
#pragma unroll
    for (int it = 0; it < 4; ++it) {
        float l = lsum[it];
        l += __shfl_xor(l, 16, 64);
        l += __shfl_xor(l, 32, 64);
        lsum[it] = 1.0f / l;
    }

    __syncthreads();                           // Vt region now reusable
    const int obase = VTH + wv * 4352;         // per-wave [16][68] f32
#pragma unroll
    for (int it = 0; it < 4; ++it) {
#pragma unroll
        for (int ct = 0; ct < 4; ++ct) {
#pragma unroll
            for (int r = 0; r < 4; ++r) {
                int c = ct * 16 + 4 * g + r;
                *reinterpret_cast<float*>(sm + obase + l15 * 272 + c * 4) =
                    acc[it][ct][r] * lsum[it];
            }
        }
        int ir = lane >> 2, cq = lane & 3;
        float* orow = vbase + (size_t)(wv * 64 + it * 16 + ir) * 64 + cq * 16;
#pragma unroll
        for (int k4 = 0; k4 < 4; ++k4) {
            float4 ov = *reinterpret_cast<const float4*>(sm + obase + ir * 272 + cq * 64 + k4 * 16);
            reinterpret_cast<float4*>(orow)[k4] = ov;
        }
    }
}

// ---------------------------------------------------------------- unblockify + residual
__global__ __launch_bounds__(256) void k_unblock(const float* __restrict__ oblk,
                                                 const float* __restrict__ x,
                                                 float* __restrict__ out) {
    int b = blockIdx.x;
    int n = b >> 8, h = b & 255;
    int t = threadIdx.x;
    int c = t & 63, wq = t >> 6;
    int kh = h & 15, jh = h >> 4;

    const float* ob = oblk + ((size_t)n << 22);
    size_t xoff = (((size_t)(n * 64 + c)) << 16) + ((size_t)h << 8);
    const float4* xr   = reinterpret_cast<const float4*>(x + xoff);
    float4*       outr = reinterpret_cast<float4*>(out + xoff);

    for (int it = 0; it < 16; ++it) {
        int w4 = wq * 16 + it;
        int w0 = w4 * 4;
        float vals[4];
#pragma unroll
        for (int r = 0; r < 4; ++r) {
            int w = w0 + r;
            int wm = w & 15, wd = w >> 4;
            vals[r] = ob[(((size_t)(kh * 16 + wm)) << 14) + ((jh * 16 + wd) << 6) + c];
        }
        float4 xv = xr[w4];
        outr[w4] = make_float4(vals[0] + xv.x, vals[1] + xv.y, vals[2] + xv.z, vals[3] + xv.w);
    }
}

// ---------------------------------------------------------------- launch
extern "C" void kernel_launch(void* const* d_in, const int* in_sizes, int n_in,
                              void* d_out, int out_size, void* d_ws, size_t ws_size,
                              hipStream_t stream) {
    const float* x       = (const float*)d_in[0];
    const float* w_match = (const float*)d_in[1];
    const float* b_match = (const float*)d_in[2];
    const float* w_asm   = (const float*)d_in[3];
    const float* b_asm   = (const float*)d_in[4];
    float* out = (float*)d_out;
    float* ws  = (float*)d_ws;

    k_transpose_w<<<1, 256, 0, stream>>>(w_asm, w_match, ws);
    k_conv1x1<<<2048, 256, 0, stream>>>(x, b_asm, ws, ws + OFF_VBLK);
    k_conv3x3<<<2048, 256, 0, stream>>>(x, b_match, ws, ws + OFF_QBLK, ws + OFF_RNORM);
    k_attn<<<2048, 256, 0, stream>>>(ws, ws + OFF_VBLK);
    k_unblock<<<2048, 256, 0, stream>>>(ws + OFF_VBLK, x, out);
}